// Round 5
// baseline (18289.995 us; speedup 1.0000x reference)
//
#include <hip/hip_runtime.h>

// NeuralODE fused persistent kernel v10 (MI355X / gfx950).
// v7 + lo-weights in registers. At 2 waves/SIMD the unified VGPR/AGPR file is
// only 25% used (each wave: 128 VGPR + 128 AGPR hi-weights; cap 256+256).
// v10 puts the per-wave lo-weight fragments (w1lo 64 + w2lo 64 regs) into the
// free AGPR space instead of LDS: removes 32 of 52 b128 LDS reads per
// wave-stage (the largest LDS stream), MFMA reads A-operands directly from
// AGPR. LDS drops to 88 KB. Numerics and barrier structure identical to v7.
// (v8 phase-offset and v9 global-weights both regressed and are reverted.)

typedef _Float16 f16;
typedef _Float16 f16x4 __attribute__((ext_vector_type(4)));
typedef _Float16 f16x8 __attribute__((ext_vector_type(8)));
typedef float    f32x4 __attribute__((ext_vector_type(4)));

#define MFMA(a, b, c) __builtin_amdgcn_mfma_f32_16x16x32_f16((a), (b), (c), 0, 0, 0)

static __device__ __forceinline__ float fast_tanh(float x) {
    // 1 - 2/(1+exp2(2*log2e*x)); e=inf -> rcp(inf)=0 -> 1.0 (safe)
    float e = __builtin_amdgcn_exp2f(x * 2.885390081777927f);
    float r = __builtin_amdgcn_rcpf(e + 1.0f);
    return __builtin_fmaf(-2.0f, r, 1.0f);
}

// f32 -> (f16 hi, f16 lo) compensated split of 4 values via packed rtz cvt.
static __device__ __forceinline__ void split4(float t0, float t1, float t2, float t3,
                                              f16x4* hv, f16x4* lv) {
    auto h01 = __builtin_amdgcn_cvt_pkrtz(t0, t1);
    auto h23 = __builtin_amdgcn_cvt_pkrtz(t2, t3);
    float l0 = t0 - (float)h01[0], l1 = t1 - (float)h01[1];
    float l2 = t2 - (float)h23[0], l3 = t3 - (float)h23[1];
    auto s01 = __builtin_amdgcn_cvt_pkrtz(l0, l1);
    auto s23 = __builtin_amdgcn_cvt_pkrtz(l2, l3);
    f16x4 h, l;
    h[0] = h01[0]; h[1] = h01[1]; h[2] = h23[0]; h[3] = h23[1];
    l[0] = s01[0]; l[1] = s01[1]; l[2] = s23[0]; l[3] = s23[1];
    *hv = h; *lv = l;
}

__global__ __launch_bounds__(512, 2) void node_fused(
    const float* __restrict__ y0g, const float* __restrict__ tg,
    const float* __restrict__ W1,  const float* __restrict__ b1,
    const float* __restrict__ W2,  const float* __restrict__ b2,
    const float* __restrict__ Wfc, const float* __restrict__ bfc,
    float* __restrict__ out)
{
    // ---- LDS: 90112 B total (lo-weights now live in AGPRs) ----
    __shared__ __align__(16) f16 wfcL [2 * 2 * 64 * 8];    // 4 KB   A-frags of Wfc (f16)
    __shared__ __align__(16) f16 hhiB[4 * 16 * 264];       // 33 KB  per-PAIR h-hi
    __shared__ __align__(16) f16 hloB[4 * 16 * 264];       // 33 KB  per-PAIR h-lo
    __shared__ __align__(16) f16 khiB[4 * 16 * 72];        // 9 KB   per-PAIR k-hi
    __shared__ __align__(16) f16 kloB[4 * 16 * 72];        // 9 KB   per-PAIR k-lo

    const int tid  = (int)threadIdx.x;
    const int wid  = tid >> 6;
    const int lane = tid & 63;
    const int q    = lane >> 4;     // quad 0..3
    const int c    = lane & 15;     // lane-in-16 (batch row within tile)
    const int pair = wid >> 1;      // 0..3 : which 16-row group
    const int half = wid & 1;       // 0..1 : which half of H / D work
    const int R0   = (int)blockIdx.x * 64 + pair * 16;
    const int jt0  = half * 8;      // GEMM1 H-tile range [jt0, jt0+8)
    const int dt0  = half * 2;      // GEMM2 D-tile range [dt0, dt0+2)

    f16* __restrict__ hhi = &hhiB[pair * 16 * 264];
    f16* __restrict__ hlo = &hloB[pair * 16 * 264];
    f16* __restrict__ khi = &khiB[pair * 16 * 72];
    f16* __restrict__ klo = &kloB[pair * 16 * 72];

    // ------------- weight A-fragments in registers (hi AND lo) -------------
    // A-layout (16x16x32): lane holds A[m = tile*16 + c][k = ks*32 + q*8 + j]
    // 4 read-only f16x8 arrays = 256 regs -> compiler places in AGPR space
    // (2 waves/SIMD x (256 AGPR + ~170 VGPR) = well under the 2048-reg pool).
    f16x8 w1a[8][2], w1l[8][2];   // W1T hi / lo, jt = jt0 + j
#pragma unroll
    for (int j = 0; j < 8; ++j)
#pragma unroll
        for (int ks = 0; ks < 2; ++ks)
#pragma unroll
            for (int jj = 0; jj < 8; ++jj) {
                float w = W1[(ks * 32 + q * 8 + jj) * 256 + (jt0 + j) * 16 + c];
                f16 hi = (f16)w;
                w1a[j][ks][jj] = hi;
                w1l[j][ks][jj] = (f16)(w - (float)hi);
            }

    f16x8 w2a[2][8], w2l[2][8];   // W2T hi / lo, dt = dt0 + d
#pragma unroll
    for (int d = 0; d < 2; ++d)
#pragma unroll
        for (int ks = 0; ks < 8; ++ks)
#pragma unroll
            for (int jj = 0; jj < 8; ++jj) {
                float w = W2[(ks * 32 + q * 8 + jj) * 64 + (dt0 + d) * 16 + c];
                f16 hi = (f16)w;
                w2a[d][ks][jj] = hi;
                w2l[d][ks][jj] = (f16)(w - (float)hi);
            }

    if (wid == 0)
        for (int ot = 0; ot < 2; ++ot)
            for (int ks = 0; ks < 2; ++ks)
                for (int j = 0; j < 8; ++j)
                    wfcL[((ot * 2 + ks) * 64 + lane) * 8 + j] =
                        (f16)Wfc[(ks * 32 + q * 8 + j) * 32 + ot * 16 + c];
    __syncthreads();   // wfc becomes read-only after this

    // biases (persistent; b1 only needed at init)
    f32x4 b2v[2], bfcv;
#pragma unroll
    for (int d = 0; d < 2; ++d)
#pragma unroll
        for (int r = 0; r < 4; ++r) b2v[d][r] = b2[(dt0 + d) * 16 + 4 * q + r];
#pragma unroll
    for (int r = 0; r < 4; ++r) bfcv[r] = bfc[half * 16 + 4 * q + r];

    // ---------------- init from y0 (split hi+lo) ----------------
    f16x8 y0hi[2], y0lo[2];
#pragma unroll
    for (int ks = 0; ks < 2; ++ks)
#pragma unroll
        for (int j = 0; j < 8; ++j) {
            float v = y0g[(R0 + c) * 64 + ks * 32 + q * 8 + j];
            f16 hi = (f16)v;
            y0hi[ks][j] = hi;
            y0lo[ks][j] = (f16)(v - (float)hi);
        }

    f32x4 P1[8];
#pragma unroll
    for (int j = 0; j < 8; ++j) {
        f32x4 cc;
#pragma unroll
        for (int r = 0; r < 4; ++r) cc[r] = b1[(jt0 + j) * 16 + 4 * q + r];
#pragma unroll
        for (int ks = 0; ks < 2; ++ks) {
            cc = MFMA(w1a[j][ks], y0hi[ks], cc);
            cc = MFMA(w1a[j][ks], y0lo[ks], cc);
            cc = MFMA(w1l[j][ks], y0hi[ks], cc);
        }
        P1[j] = cc;
    }
    // fc of y0: this wave produces output tile ot = half
    f32x4 pfc;
    {
        f32x4 z = {0.f, 0.f, 0.f, 0.f};
#pragma unroll
        for (int ks = 0; ks < 2; ++ks) {
            f16x8 wa = *reinterpret_cast<const f16x8*>(&wfcL[((half * 2 + ks) * 64 + lane) * 8]);
            z = MFMA(wa, y0hi[ks], z);
            z = MFMA(wa, y0lo[ks], z);
        }
        pfc = z;
    }
    {
        f32x4 v = pfc + bfcv;
        *reinterpret_cast<f32x4*>(&out[(size_t)(R0 + c) * 32 + half * 16 + 4 * q]) = v;
    }

    f32x4 ksum[2], dy[2];
#pragma unroll
    for (int d = 0; d < 2; ++d) dy[d] = f32x4{0.f, 0.f, 0.f, 0.f};

    // ---- bootstrap: h1 = tanh(P1) for this wave's jt half -> pair LDS ----
#pragma unroll
    for (int j = 0; j < 8; ++j) {
        float t0 = fast_tanh(P1[j][0]), t1 = fast_tanh(P1[j][1]);
        float t2 = fast_tanh(P1[j][2]), t3 = fast_tanh(P1[j][3]);
        f16x4 hv, lv;
        split4(t0, t1, t2, t3, &hv, &lv);
        *reinterpret_cast<f16x4*>(&hhi[c * 264 + (jt0 + j) * 16 + 4 * q]) = hv;
        *reinterpret_cast<f16x4*>(&hlo[c * 264 + (jt0 + j) * 16 + 4 * q]) = lv;
    }
    __syncthreads();

    float hh = 0.f, ch = 0.f, c6 = 0.f;

    // GEMM2half (D-split): k[dt0..dt0+1] = hhi@W2hi + hlo@W2hi + hhi@W2lo + b2
    // over FULL H (pair-shared h). ksum accumulate; split k (or c6*ksum) -> LDS.
    auto gemm2half = [&](float w, bool first, bool last) {
        f32x4 ka[2];
#pragma unroll
        for (int d = 0; d < 2; ++d) ka[d] = b2v[d];
#pragma unroll
        for (int ks = 0; ks < 8; ++ks) {
            f16x8 bhi = *reinterpret_cast<const f16x8*>(&hhi[c * 264 + ks * 32 + q * 8]);
            f16x8 blo = *reinterpret_cast<const f16x8*>(&hlo[c * 264 + ks * 32 + q * 8]);
#pragma unroll
            for (int d = 0; d < 2; ++d) {
                ka[d] = MFMA(w2a[d][ks], bhi, ka[d]);
                ka[d] = MFMA(w2a[d][ks], blo, ka[d]);
                ka[d] = MFMA(w2l[d][ks], bhi, ka[d]);
            }
        }
#pragma unroll
        for (int d = 0; d < 2; ++d) {
            if (first)      ksum[d] = ka[d];
            else            ksum[d] += ka[d] * w;
            f32x4 kv;
            if (!last) {
                kv = ka[d];
            } else {
                kv = ksum[d] * c6;
                dy[d] += kv;
            }
            f16x4 hv, lv;
            split4(kv[0], kv[1], kv[2], kv[3], &hv, &lv);
            *reinterpret_cast<f16x4*>(&khi[c * 72 + (dt0 + d) * 16 + 4 * q]) = hv;
            *reinterpret_cast<f16x4*>(&klo[c * 72 + (dt0 + d) * 16 + 4 * q]) = lv;
        }
        __syncthreads();
    };

    // GEMM1half (H-split): per j in this wave's jt half: z = W1T@k (full D),
    // then a = P1 + carg*z (or final: P1 += z; a = P1), tanh, split -> pair h.
    auto gemm1half = [&](float carg, bool fin) {
        f16x8 kh0 = *reinterpret_cast<const f16x8*>(&khi[c * 72 + q * 8]);
        f16x8 kh1 = *reinterpret_cast<const f16x8*>(&khi[c * 72 + 32 + q * 8]);
        f16x8 kl0 = *reinterpret_cast<const f16x8*>(&klo[c * 72 + q * 8]);
        f16x8 kl1 = *reinterpret_cast<const f16x8*>(&klo[c * 72 + 32 + q * 8]);
#pragma unroll
        for (int j = 0; j < 8; ++j) {
            int jt = jt0 + j;
            f32x4 z = {0.f, 0.f, 0.f, 0.f};
            z = MFMA(w1a[j][0], kh0, z);
            z = MFMA(w1a[j][0], kl0, z);
            z = MFMA(w1l[j][0], kh0, z);
            z = MFMA(w1a[j][1], kh1, z);
            z = MFMA(w1a[j][1], kl1, z);
            z = MFMA(w1l[j][1], kh1, z);
            float a0f, a1f, a2f, a3f;
            if (fin) {
                P1[j] += z;
                a0f = P1[j][0]; a1f = P1[j][1]; a2f = P1[j][2]; a3f = P1[j][3];
            } else {
                a0f = __builtin_fmaf(carg, z[0], P1[j][0]);
                a1f = __builtin_fmaf(carg, z[1], P1[j][1]);
                a2f = __builtin_fmaf(carg, z[2], P1[j][2]);
                a3f = __builtin_fmaf(carg, z[3], P1[j][3]);
            }
            float t0 = fast_tanh(a0f), t1 = fast_tanh(a1f);
            float t2 = fast_tanh(a2f), t3 = fast_tanh(a3f);
            f16x4 hv, lv;
            split4(t0, t1, t2, t3, &hv, &lv);
            *reinterpret_cast<f16x4*>(&hhi[c * 264 + jt * 16 + 4 * q]) = hv;
            *reinterpret_cast<f16x4*>(&hlo[c * 264 + jt * 16 + 4 * q]) = lv;
        }
        __syncthreads();
    };

#pragma unroll 1
    for (int ti = 0; ti < 49; ++ti) {
        float dtv = tg[ti + 1] - tg[ti];
        hh = dtv * 0.125f;
        ch = 0.5f * hh;
        c6 = hh * (1.0f / 6.0f);
#pragma unroll 1
        for (int sub = 0; sub < 8; ++sub) {
            gemm2half(1.0f, true,  false);  // k1;       ksum  = k1
            gemm1half(ch, false);           // h2 = tanh(P1 + ch*U1)
            gemm2half(2.0f, false, false);  // k2;       ksum += 2*k2
            gemm1half(ch, false);           // h3
            gemm2half(2.0f, false, false);  // k3;       ksum += 2*k3
            gemm1half(hh, false);           // h4
            gemm2half(1.0f, false, true);   // k4; ksum += k4; kv = c6*ksum; dy += kv
            gemm1half(0.0f, true);          // P1 += W1T@kv; h1' = tanh(P1)
        }
        // ---- interval epilogue: pfc += dy @ Wfc (dy split hi+lo, pair-merged) ----
#pragma unroll
        for (int d = 0; d < 2; ++d) {
            f16x4 hv, lv;
            split4(dy[d][0], dy[d][1], dy[d][2], dy[d][3], &hv, &lv);
            *reinterpret_cast<f16x4*>(&khi[c * 72 + (dt0 + d) * 16 + 4 * q]) = hv;
            *reinterpret_cast<f16x4*>(&klo[c * 72 + (dt0 + d) * 16 + 4 * q]) = lv;
            dy[d] = f32x4{0.f, 0.f, 0.f, 0.f};
        }
        __syncthreads();
        {
            f16x8 dh0 = *reinterpret_cast<const f16x8*>(&khi[c * 72 + q * 8]);
            f16x8 dh1 = *reinterpret_cast<const f16x8*>(&khi[c * 72 + 32 + q * 8]);
            f16x8 dl0 = *reinterpret_cast<const f16x8*>(&klo[c * 72 + q * 8]);
            f16x8 dl1 = *reinterpret_cast<const f16x8*>(&klo[c * 72 + 32 + q * 8]);
            f16x8 wa0 = *reinterpret_cast<const f16x8*>(&wfcL[((half * 2 + 0) * 64 + lane) * 8]);
            f16x8 wa1 = *reinterpret_cast<const f16x8*>(&wfcL[((half * 2 + 1) * 64 + lane) * 8]);
            pfc = MFMA(wa0, dh0, pfc);
            pfc = MFMA(wa0, dl0, pfc);
            pfc = MFMA(wa1, dh1, pfc);
            pfc = MFMA(wa1, dl1, pfc);
        }
        __syncthreads();   // epilogue k-reads drained before next interval's k-writes
        size_t base = (size_t)(ti + 1) * (16384 * 32);
        {
            f32x4 v = pfc + bfcv;
            *reinterpret_cast<f32x4*>(&out[base + (size_t)(R0 + c) * 32 + half * 16 + 4 * q]) = v;
        }
    }
}

extern "C" void kernel_launch(void* const* d_in, const int* in_sizes, int n_in,
                              void* d_out, int out_size, void* d_ws, size_t ws_size,
                              hipStream_t stream) {
    (void)in_sizes; (void)n_in; (void)d_ws; (void)ws_size; (void)out_size;
    const float* y0  = (const float*)d_in[0];
    const float* t   = (const float*)d_in[1];
    const float* W1  = (const float*)d_in[2];
    const float* b1  = (const float*)d_in[3];
    const float* W2  = (const float*)d_in[4];
    const float* b2  = (const float*)d_in[5];
    const float* Wfc = (const float*)d_in[6];
    const float* bfc = (const float*)d_in[7];
    float* out = (float*)d_out;
    // 256 blocks x 512 threads: 8 waves (4 row-pairs x 2 halves), 1 block/CU,
    // 2 waves/SIMD; hi+lo weight fragments in the unified VGPR/AGPR file.
    node_fused<<<dim3(256), dim3(512), 0, stream>>>(y0, t, W1, b1, W2, b2, Wfc, bfc, out);
}

// Round 6
// 4295.090 us; speedup vs baseline: 4.2583x; 4.2583x over previous
//
#include <hip/hip_runtime.h>

// NeuralODE fused persistent kernel v11 (MI355X / gfx950).
// v7 + mixed-precision RK stages. The state path (ksum -> P1 update via the
// FINAL gemm1, and all gemm2 k-accumulations) keeps the full 3-term
// split-f16 GEMMs. The argument path (h2,h3,h4 = tanh(P1 + c*U), c~0.06dt)
// drops the lo-correction terms: intermediate gemm1s use 2 MFMA/jt instead
// of 6 (no W1lo@k, no W1hi@klo), and k1..k3 skip the k-lo split/write.
// Cuts per-wave-stage MFMA 96->72 and LDS b128 reads 52->38.5 while leaving
// the accumulated-state numerics at v7 precision.
// (v8 phase-offset, v9 global weights, v10 reg-lo-weights all regressed:
//  unified RF budget is 256 regs/wave TOTAL at 2 waves/SIMD - v7 is full.)

typedef _Float16 f16;
typedef _Float16 f16x4 __attribute__((ext_vector_type(4)));
typedef _Float16 f16x8 __attribute__((ext_vector_type(8)));
typedef float    f32x4 __attribute__((ext_vector_type(4)));

#define MFMA(a, b, c) __builtin_amdgcn_mfma_f32_16x16x32_f16((a), (b), (c), 0, 0, 0)

static __device__ __forceinline__ float fast_tanh(float x) {
    // 1 - 2/(1+exp2(2*log2e*x)); e=inf -> rcp(inf)=0 -> 1.0 (safe)
    float e = __builtin_amdgcn_exp2f(x * 2.885390081777927f);
    float r = __builtin_amdgcn_rcpf(e + 1.0f);
    return __builtin_fmaf(-2.0f, r, 1.0f);
}

// f32 -> (f16 hi, f16 lo) compensated split of 4 values via packed rtz cvt.
static __device__ __forceinline__ void split4(float t0, float t1, float t2, float t3,
                                              f16x4* hv, f16x4* lv) {
    auto h01 = __builtin_amdgcn_cvt_pkrtz(t0, t1);
    auto h23 = __builtin_amdgcn_cvt_pkrtz(t2, t3);
    float l0 = t0 - (float)h01[0], l1 = t1 - (float)h01[1];
    float l2 = t2 - (float)h23[0], l3 = t3 - (float)h23[1];
    auto s01 = __builtin_amdgcn_cvt_pkrtz(l0, l1);
    auto s23 = __builtin_amdgcn_cvt_pkrtz(l2, l3);
    f16x4 h, l;
    h[0] = h01[0]; h[1] = h01[1]; h[2] = h23[0]; h[3] = h23[1];
    l[0] = s01[0]; l[1] = s01[1]; l[2] = s23[0]; l[3] = s23[1];
    *hv = h; *lv = l;
}

__global__ __launch_bounds__(512, 2) void node_fused(
    const float* __restrict__ y0g, const float* __restrict__ tg,
    const float* __restrict__ W1,  const float* __restrict__ b1,
    const float* __restrict__ W2,  const float* __restrict__ b2,
    const float* __restrict__ Wfc, const float* __restrict__ bfc,
    float* __restrict__ out)
{
    // ---- LDS: 155648 B total ----
    __shared__ __align__(16) f16 w1loL[16 * 2 * 64 * 8];   // 32 KB  A-frags of W1lo
    __shared__ __align__(16) f16 w2loL[4 * 8 * 64 * 8];    // 32 KB  A-frags of W2lo
    __shared__ __align__(16) f16 wfcL [2 * 2 * 64 * 8];    // 4 KB   A-frags of Wfc (f16)
    __shared__ __align__(16) f16 hhiB[4 * 16 * 264];       // 33 KB  per-PAIR h-hi
    __shared__ __align__(16) f16 hloB[4 * 16 * 264];       // 33 KB  per-PAIR h-lo
    __shared__ __align__(16) f16 khiB[4 * 16 * 72];        // 9 KB   per-PAIR k-hi
    __shared__ __align__(16) f16 kloB[4 * 16 * 72];        // 9 KB   per-PAIR k-lo

    const int tid  = (int)threadIdx.x;
    const int wid  = tid >> 6;
    const int lane = tid & 63;
    const int q    = lane >> 4;     // quad 0..3
    const int c    = lane & 15;     // lane-in-16 (batch row within tile)
    const int pair = wid >> 1;      // 0..3 : which 16-row group
    const int half = wid & 1;       // 0..1 : which half of H / D work
    const int R0   = (int)blockIdx.x * 64 + pair * 16;
    const int jt0  = half * 8;      // GEMM1 H-tile range [jt0, jt0+8)
    const int dt0  = half * 2;      // GEMM2 D-tile range [dt0, dt0+2)

    f16* __restrict__ hhi = &hhiB[pair * 16 * 264];
    f16* __restrict__ hlo = &hloB[pair * 16 * 264];
    f16* __restrict__ khi = &khiB[pair * 16 * 72];
    f16* __restrict__ klo = &kloB[pair * 16 * 72];

    // ---------------- hi-weight A-fragments in registers ----------------
    // A-layout (16x16x32): lane holds A[m = tile*16 + c][k = ks*32 + q*8 + j]
    f16x8 w1a[8][2];    // W1T hi, jt = jt0 + j
#pragma unroll
    for (int j = 0; j < 8; ++j)
#pragma unroll
        for (int ks = 0; ks < 2; ++ks)
#pragma unroll
            for (int jj = 0; jj < 8; ++jj)
                w1a[j][ks][jj] = (f16)W1[(ks * 32 + q * 8 + jj) * 256 + (jt0 + j) * 16 + c];

    f16x8 w2a[2][8];    // W2T hi, dt = dt0 + d
#pragma unroll
    for (int d = 0; d < 2; ++d)
#pragma unroll
        for (int ks = 0; ks < 8; ++ks)
#pragma unroll
            for (int jj = 0; jj < 8; ++jj)
                w2a[d][ks][jj] = (f16)W2[(ks * 32 + q * 8 + jj) * 64 + (dt0 + d) * 16 + c];

    // ---------------- lo-weight A-fragments -> LDS (split across 8 waves) ----
    for (int jr = 0; jr < 2; ++jr) {
        int jt = wid * 2 + jr;
        for (int ks = 0; ks < 2; ++ks)
            for (int j = 0; j < 8; ++j) {
                float w = W1[(ks * 32 + q * 8 + j) * 256 + jt * 16 + c];
                f16 hi = (f16)w;
                w1loL[((jt * 2 + ks) * 64 + lane) * 8 + j] = (f16)(w - (float)hi);
            }
    }
    {
        int dt = wid >> 1;
        for (int kr = 0; kr < 4; ++kr) {
            int ks = (wid & 1) * 4 + kr;
            for (int j = 0; j < 8; ++j) {
                float w = W2[(ks * 32 + q * 8 + j) * 64 + dt * 16 + c];
                f16 hi = (f16)w;
                w2loL[((dt * 8 + ks) * 64 + lane) * 8 + j] = (f16)(w - (float)hi);
            }
        }
    }
    if (wid == 0)
        for (int ot = 0; ot < 2; ++ot)
            for (int ks = 0; ks < 2; ++ks)
                for (int j = 0; j < 8; ++j)
                    wfcL[((ot * 2 + ks) * 64 + lane) * 8 + j] =
                        (f16)Wfc[(ks * 32 + q * 8 + j) * 32 + ot * 16 + c];
    __syncthreads();   // weights become read-only after this

    // biases (persistent; b1 only needed at init)
    f32x4 b2v[2], bfcv;
#pragma unroll
    for (int d = 0; d < 2; ++d)
#pragma unroll
        for (int r = 0; r < 4; ++r) b2v[d][r] = b2[(dt0 + d) * 16 + 4 * q + r];
#pragma unroll
    for (int r = 0; r < 4; ++r) bfcv[r] = bfc[half * 16 + 4 * q + r];

    // ---------------- init from y0 (split hi+lo) ----------------
    f16x8 y0hi[2], y0lo[2];
#pragma unroll
    for (int ks = 0; ks < 2; ++ks)
#pragma unroll
        for (int j = 0; j < 8; ++j) {
            float v = y0g[(R0 + c) * 64 + ks * 32 + q * 8 + j];
            f16 hi = (f16)v;
            y0hi[ks][j] = hi;
            y0lo[ks][j] = (f16)(v - (float)hi);
        }

    f32x4 P1[8];
#pragma unroll
    for (int j = 0; j < 8; ++j) {
        f32x4 cc;
#pragma unroll
        for (int r = 0; r < 4; ++r) cc[r] = b1[(jt0 + j) * 16 + 4 * q + r];
#pragma unroll
        for (int ks = 0; ks < 2; ++ks) {
            f16x8 alo = *reinterpret_cast<const f16x8*>(&w1loL[(((jt0 + j) * 2 + ks) * 64 + lane) * 8]);
            cc = MFMA(w1a[j][ks], y0hi[ks], cc);
            cc = MFMA(w1a[j][ks], y0lo[ks], cc);
            cc = MFMA(alo,        y0hi[ks], cc);
        }
        P1[j] = cc;
    }
    // fc of y0: this wave produces output tile ot = half
    f32x4 pfc;
    {
        f32x4 z = {0.f, 0.f, 0.f, 0.f};
#pragma unroll
        for (int ks = 0; ks < 2; ++ks) {
            f16x8 wa = *reinterpret_cast<const f16x8*>(&wfcL[((half * 2 + ks) * 64 + lane) * 8]);
            z = MFMA(wa, y0hi[ks], z);
            z = MFMA(wa, y0lo[ks], z);
        }
        pfc = z;
    }
    {
        f32x4 v = pfc + bfcv;
        *reinterpret_cast<f32x4*>(&out[(size_t)(R0 + c) * 32 + half * 16 + 4 * q]) = v;
    }

    f32x4 ksum[2], dy[2];
#pragma unroll
    for (int d = 0; d < 2; ++d) dy[d] = f32x4{0.f, 0.f, 0.f, 0.f};

    // ---- bootstrap: h1 = tanh(P1) for this wave's jt half -> pair LDS ----
#pragma unroll
    for (int j = 0; j < 8; ++j) {
        float t0 = fast_tanh(P1[j][0]), t1 = fast_tanh(P1[j][1]);
        float t2 = fast_tanh(P1[j][2]), t3 = fast_tanh(P1[j][3]);
        f16x4 hv, lv;
        split4(t0, t1, t2, t3, &hv, &lv);
        *reinterpret_cast<f16x4*>(&hhi[c * 264 + (jt0 + j) * 16 + 4 * q]) = hv;
        *reinterpret_cast<f16x4*>(&hlo[c * 264 + (jt0 + j) * 16 + 4 * q]) = lv;
    }
    __syncthreads();

    float hh = 0.f, ch = 0.f, c6 = 0.f;

    // GEMM2half (D-split): k[dt0..dt0+1] = hhi@W2hi + hlo@W2hi + hhi@W2lo + b2
    // over FULL H (pair-shared h). ksum accumulate (always full precision).
    // k1..k3 (!last): write k-hi only (RNE) - consumed by lite gemm1s.
    // k4 (last): kv = c6*ksum, full hi+lo split - consumed by the fin gemm1.
    auto gemm2half = [&](float w, bool first, bool last) {
        f32x4 ka[2];
#pragma unroll
        for (int d = 0; d < 2; ++d) ka[d] = b2v[d];
#pragma unroll
        for (int ks = 0; ks < 8; ++ks) {
            f16x8 bhi = *reinterpret_cast<const f16x8*>(&hhi[c * 264 + ks * 32 + q * 8]);
            f16x8 blo = *reinterpret_cast<const f16x8*>(&hlo[c * 264 + ks * 32 + q * 8]);
#pragma unroll
            for (int d = 0; d < 2; ++d) {
                f16x8 alo = *reinterpret_cast<const f16x8*>(&w2loL[(((dt0 + d) * 8 + ks) * 64 + lane) * 8]);
                ka[d] = MFMA(w2a[d][ks], bhi, ka[d]);
                ka[d] = MFMA(w2a[d][ks], blo, ka[d]);
                ka[d] = MFMA(alo,        bhi, ka[d]);
            }
        }
#pragma unroll
        for (int d = 0; d < 2; ++d) {
            if (first)      ksum[d] = ka[d];
            else            ksum[d] += ka[d] * w;
            if (!last) {
                // argument-path k: hi only, RNE rounding
                f16x4 hv;
                hv[0] = (f16)ka[d][0]; hv[1] = (f16)ka[d][1];
                hv[2] = (f16)ka[d][2]; hv[3] = (f16)ka[d][3];
                *reinterpret_cast<f16x4*>(&khi[c * 72 + (dt0 + d) * 16 + 4 * q]) = hv;
            } else {
                f32x4 kv = ksum[d] * c6;
                dy[d] += kv;
                f16x4 hv, lv;
                split4(kv[0], kv[1], kv[2], kv[3], &hv, &lv);
                *reinterpret_cast<f16x4*>(&khi[c * 72 + (dt0 + d) * 16 + 4 * q]) = hv;
                *reinterpret_cast<f16x4*>(&klo[c * 72 + (dt0 + d) * 16 + 4 * q]) = lv;
            }
        }
        __syncthreads();
    };

    // GEMM1half (H-split): per j in this wave's jt half: z = W1T@k (full D).
    // !fin (argument path): 2 MFMA/jt (hi-weights @ k-hi only).
    // fin  (state path):    6 MFMA/jt (full split: +W1hi@klo +W1lo@khi).
    auto gemm1half = [&](float carg, bool fin) {
        f16x8 kh0 = *reinterpret_cast<const f16x8*>(&khi[c * 72 + q * 8]);
        f16x8 kh1 = *reinterpret_cast<const f16x8*>(&khi[c * 72 + 32 + q * 8]);
        f16x8 kl0, kl1;
        if (fin) {
            kl0 = *reinterpret_cast<const f16x8*>(&klo[c * 72 + q * 8]);
            kl1 = *reinterpret_cast<const f16x8*>(&klo[c * 72 + 32 + q * 8]);
        }
#pragma unroll
        for (int j = 0; j < 8; ++j) {
            int jt = jt0 + j;
            f32x4 z = {0.f, 0.f, 0.f, 0.f};
            if (fin) {
                f16x8 a0 = *reinterpret_cast<const f16x8*>(&w1loL[((jt * 2 + 0) * 64 + lane) * 8]);
                f16x8 a1 = *reinterpret_cast<const f16x8*>(&w1loL[((jt * 2 + 1) * 64 + lane) * 8]);
                z = MFMA(w1a[j][0], kh0, z);
                z = MFMA(w1a[j][0], kl0, z);
                z = MFMA(a0,        kh0, z);
                z = MFMA(w1a[j][1], kh1, z);
                z = MFMA(w1a[j][1], kl1, z);
                z = MFMA(a1,        kh1, z);
            } else {
                z = MFMA(w1a[j][0], kh0, z);
                z = MFMA(w1a[j][1], kh1, z);
            }
            float a0f, a1f, a2f, a3f;
            if (fin) {
                P1[j] += z;
                a0f = P1[j][0]; a1f = P1[j][1]; a2f = P1[j][2]; a3f = P1[j][3];
            } else {
                a0f = __builtin_fmaf(carg, z[0], P1[j][0]);
                a1f = __builtin_fmaf(carg, z[1], P1[j][1]);
                a2f = __builtin_fmaf(carg, z[2], P1[j][2]);
                a3f = __builtin_fmaf(carg, z[3], P1[j][3]);
            }
            float t0 = fast_tanh(a0f), t1 = fast_tanh(a1f);
            float t2 = fast_tanh(a2f), t3 = fast_tanh(a3f);
            f16x4 hv, lv;
            split4(t0, t1, t2, t3, &hv, &lv);
            *reinterpret_cast<f16x4*>(&hhi[c * 264 + jt * 16 + 4 * q]) = hv;
            *reinterpret_cast<f16x4*>(&hlo[c * 264 + jt * 16 + 4 * q]) = lv;
        }
        __syncthreads();
    };

#pragma unroll 1
    for (int ti = 0; ti < 49; ++ti) {
        float dtv = tg[ti + 1] - tg[ti];
        hh = dtv * 0.125f;
        ch = 0.5f * hh;
        c6 = hh * (1.0f / 6.0f);
#pragma unroll 1
        for (int sub = 0; sub < 8; ++sub) {
            gemm2half(1.0f, true,  false);  // k1;       ksum  = k1
            gemm1half(ch, false);           // h2 = tanh(P1 + ch*U1)   [lite]
            gemm2half(2.0f, false, false);  // k2;       ksum += 2*k2
            gemm1half(ch, false);           // h3                      [lite]
            gemm2half(2.0f, false, false);  // k3;       ksum += 2*k3
            gemm1half(hh, false);           // h4                      [lite]
            gemm2half(1.0f, false, true);   // k4; ksum += k4; kv = c6*ksum; dy += kv
            gemm1half(0.0f, true);          // P1 += W1T@kv (full); h1' = tanh(P1)
        }
        // ---- interval epilogue: pfc += dy @ Wfc (dy split hi+lo, pair-merged) ----
#pragma unroll
        for (int d = 0; d < 2; ++d) {
            f16x4 hv, lv;
            split4(dy[d][0], dy[d][1], dy[d][2], dy[d][3], &hv, &lv);
            *reinterpret_cast<f16x4*>(&khi[c * 72 + (dt0 + d) * 16 + 4 * q]) = hv;
            *reinterpret_cast<f16x4*>(&klo[c * 72 + (dt0 + d) * 16 + 4 * q]) = lv;
            dy[d] = f32x4{0.f, 0.f, 0.f, 0.f};
        }
        __syncthreads();
        {
            f16x8 dh0 = *reinterpret_cast<const f16x8*>(&khi[c * 72 + q * 8]);
            f16x8 dh1 = *reinterpret_cast<const f16x8*>(&khi[c * 72 + 32 + q * 8]);
            f16x8 dl0 = *reinterpret_cast<const f16x8*>(&klo[c * 72 + q * 8]);
            f16x8 dl1 = *reinterpret_cast<const f16x8*>(&klo[c * 72 + 32 + q * 8]);
            f16x8 wa0 = *reinterpret_cast<const f16x8*>(&wfcL[((half * 2 + 0) * 64 + lane) * 8]);
            f16x8 wa1 = *reinterpret_cast<const f16x8*>(&wfcL[((half * 2 + 1) * 64 + lane) * 8]);
            pfc = MFMA(wa0, dh0, pfc);
            pfc = MFMA(wa0, dl0, pfc);
            pfc = MFMA(wa1, dh1, pfc);
            pfc = MFMA(wa1, dl1, pfc);
        }
        __syncthreads();   // epilogue k-reads drained before next interval's k-writes
        size_t base = (size_t)(ti + 1) * (16384 * 32);
        {
            f32x4 v = pfc + bfcv;
            *reinterpret_cast<f32x4*>(&out[base + (size_t)(R0 + c) * 32 + half * 16 + 4 * q]) = v;
        }
    }
}

extern "C" void kernel_launch(void* const* d_in, const int* in_sizes, int n_in,
                              void* d_out, int out_size, void* d_ws, size_t ws_size,
                              hipStream_t stream) {
    (void)in_sizes; (void)n_in; (void)d_ws; (void)ws_size; (void)out_size;
    const float* y0  = (const float*)d_in[0];
    const float* t   = (const float*)d_in[1];
    const float* W1  = (const float*)d_in[2];
    const float* b1  = (const float*)d_in[3];
    const float* W2  = (const float*)d_in[4];
    const float* b2  = (const float*)d_in[5];
    const float* Wfc = (const float*)d_in[6];
    const float* bfc = (const float*)d_in[7];
    float* out = (float*)d_out;
    // 256 blocks x 512 threads: 8 waves (4 row-pairs x 2 halves), 1 block/CU,
    // 2 waves/SIMD; mixed-precision RK: full split on state path, lite args.
    node_fused<<<dim3(256), dim3(512), 0, stream>>>(y0, t, W1, b1, W2, b2, Wfc, bfc, out);
}